// Round 14
// baseline (101.738 us; speedup 1.0000x reference)
//
#include <hip/hip_runtime.h>
#include <hip/hip_bf16.h>
#include <math.h>

#define BS 2
#define NHEADS 8
#define HD 32
#define DIM 256
#define W3 768          // 3*DIM
#define S_MAIN 1536
#define S_AUX 768
#define SM_TOT 3072
#define S_TOT 4608

typedef _Float16 f16x8 __attribute__((ext_vector_type(8)));
typedef _Float16 f16x4 __attribute__((ext_vector_type(4)));
typedef float    f32x4 __attribute__((ext_vector_type(4)));

// 1/sqrt(32) * log2(e): Q pre-scaled so softmax runs in exp2 domain
#define QK_SCALE 0.25503491f

// ---- workspace layout ----
// halves:
#define QM_H  0
#define KM_H  1572864
#define VMT_H 3145728
#define QA_H  4718592
#define KA_H  5505024
#define VAT_H 6291456
// fp16 x (aliases AO0 float region — consumed by qkv BEFORE attn writes AO0):
#define XH_H  7077888
// floats:
#define AO0_F 3538944
#define AO1_F 5898240
#define L0_F  8257536
#define L1_F  8266752
// fp16 transposed weights (after L1; bytes 33,103,872..35,201,024):
#define WT1_H 16551936   // Wqkv^T  [4][768][256]
#define WT2_H 17338368   // Wproj^T [4][256][256]

// async global->LDS, 16B per lane, dest = wave-uniform base + lane*16
#define GLOAD_LDS(SRC, DST)                                                    \
    __builtin_amdgcn_global_load_lds(                                          \
        (const __attribute__((address_space(1))) void*)(SRC),                  \
        (__attribute__((address_space(3))) void*)(DST), 16, 0, 0)

// ---------------------------------------------------------------------------
// Kernel 0: operand pre-convert.
//  blocks 0..1151:   x (4 mods) fp32 -> fp16 xh, 8 elems/thread
//  blocks 1152..1199: Wqkv  [m][k][col] -> fp16 Wt1[m][col][k]
//  blocks 1200..1215: Wproj [m][k][col] -> fp16 Wt2[m][col][k]
// ---------------------------------------------------------------------------
__global__ __launch_bounds__(256) void convert_kernel(
    const float* __restrict__ x0, const float* __restrict__ x1,
    const float* __restrict__ x2, const float* __restrict__ x3,
    const float* __restrict__ Wqkv, const float* __restrict__ Wproj,
    _Float16* __restrict__ wsh)
{
    const int bid = blockIdx.x;
    const int t   = threadIdx.x;

    if (bid < 1152) {                        // x convert
        const float* src;
        int off;                             // half offset within xh
        if (bid < 384)      { src = x0; off = (bid      ) * 2048; }
        else if (bid < 768) { src = x1 - 786432 + 0;  off = bid * 2048; }
        else if (bid < 960) { src = x2; off = 1572864 + (bid - 768) * 2048; }
        else                { src = x3; off = 1966080 + (bid - 960) * 2048; }
        const int base = (bid < 384) ? bid * 2048
                       : (bid < 768) ? (bid - 384) * 2048
                       : (bid < 960) ? (bid - 768) * 2048
                       : (bid - 960) * 2048;
        const float* p = ((bid < 384) ? x0 : (bid < 768) ? x1
                         : (bid < 960) ? x2 : x3) + base + t * 8;
        _Float16* dst = wsh + XH_H + off + t * 8;
        const float4 u0 = *(const float4*)(p + 0);
        const float4 u1 = *(const float4*)(p + 4);
        f16x8 h;
        h[0] = (_Float16)u0.x; h[1] = (_Float16)u0.y;
        h[2] = (_Float16)u0.z; h[3] = (_Float16)u0.w;
        h[4] = (_Float16)u1.x; h[5] = (_Float16)u1.y;
        h[6] = (_Float16)u1.z; h[7] = (_Float16)u1.w;
        *(f16x8*)dst = h;
    } else if (bid < 1200) {                 // Wqkv transpose
        const int i  = bid - 1152;
        const int m  = i / 12;
        const int cc = i % 12;
        const int col = cc * 64 + (t & 63);
        const int kq  = t >> 6;
        const float* Wm = Wqkv + m * (DIM * W3);
        _Float16*   Wt  = wsh + WT1_H + m * (W3 * DIM) + col * DIM;
        #pragma unroll 4
        for (int k = kq * 64; k < kq * 64 + 64; ++k)
            Wt[k] = (_Float16)Wm[k * W3 + col];
    } else {                                 // Wproj transpose
        const int i  = bid - 1200;
        const int m  = i / 4;
        const int cc = i % 4;
        const int col = cc * 64 + (t & 63);
        const int kq  = t >> 6;
        const float* Wm = Wproj + m * (DIM * DIM);
        _Float16*   Wt  = wsh + WT2_H + m * (DIM * DIM) + col * DIM;
        #pragma unroll 4
        for (int k = kq * 64; k < kq * 64 + 64; ++k)
            Wt[k] = (_Float16)Wm[k * DIM + col];
    }
}

// ---------------------------------------------------------------------------
// Kernel 1: QKV projection, fp16 MFMA. Staging now pure f16x8 vector copies
// from pre-converted xh / Wt1 (LDS layouts, MFMA, epilogue unchanged).
// ---------------------------------------------------------------------------
__global__ __launch_bounds__(256) void qkv_mfma_kernel(
    const _Float16* __restrict__ wsh_ro, const float* __restrict__ bqkv,
    _Float16* __restrict__ wsh)
{
    const int m  = blockIdx.z;
    const int rt = blockIdx.y;
    const int ct = blockIdx.x;
    const int s_m   = (m < 2) ? S_MAIN : S_AUX;
    const int nrows = BS * s_m;
    const int r0 = rt * 128;
    if (r0 >= nrows) return;

    const int xoff = (m == 0) ? 0 : (m == 1) ? 786432
                   : (m == 2) ? 1572864 : 1966080;
    const _Float16* xh = wsh_ro + XH_H + xoff;
    const _Float16* Wt = wsh_ro + WT1_H + m * (W3 * DIM);
    const float* bias  = bqkv + m * W3;

    __shared__ _Float16 As[128][40];
    __shared__ _Float16 Bs[64][40];

    const int t    = threadIdx.x;
    const int wid  = t >> 6;
    const int lane = t & 63;
    const int g    = lane >> 4;
    const int c    = lane & 15;
    const int c0   = ct * 64;

    const int arow = t >> 1;
    const int ak   = (t & 1) << 4;
    const int bcol = t & 63;
    const int bkg  = t >> 6;
    const int bsg  = bkg ^ ((bcol >> 3) & 3);

    f32x4 acc[2][4];
    #pragma unroll
    for (int i = 0; i < 2; ++i)
        #pragma unroll
        for (int j = 0; j < 4; ++j)
            acc[i][j] = (f32x4){0.f, 0.f, 0.f, 0.f};

    const _Float16* xp = xh + (r0 + arow) * DIM + ak;
    const _Float16* wp = Wt + (c0 + bcol) * DIM;

    for (int kk = 0; kk < DIM; kk += 32) {
        {
            const f16x8 h0 = *(const f16x8*)(xp + kk);
            const f16x8 h1 = *(const f16x8*)(xp + kk + 8);
            *(f16x8*)&As[arow][ak]     = h0;
            *(f16x8*)&As[arow][ak + 8] = h1;
        }
        {
            const f16x8 hb = *(const f16x8*)(wp + kk + bkg * 8);
            *(f16x8*)&Bs[bcol][bsg << 3] = hb;
        }
        __syncthreads();
        const f16x8 af0 = *(const f16x8*)&As[wid * 32 + c][g * 8];
        const f16x8 af1 = *(const f16x8*)&As[wid * 32 + 16 + c][g * 8];
        #pragma unroll
        for (int j = 0; j < 4; ++j) {
            const int bc = j * 16 + c;
            const int gg = g ^ ((bc >> 3) & 3);
            const f16x8 bf = *(const f16x8*)&Bs[bc][gg * 8];
            acc[0][j] = __builtin_amdgcn_mfma_f32_16x16x32_f16(af0, bf, acc[0][j], 0, 0, 0);
            acc[1][j] = __builtin_amdgcn_mfma_f32_16x16x32_f16(af1, bf, acc[1][j], 0, 0, 0);
        }
        __syncthreads();
    }

    #pragma unroll
    for (int i = 0; i < 2; ++i) {
        const int gr = r0 + wid * 32 + i * 16 + 4 * g;
        const int b  = (gr >= s_m) ? 1 : 0;
        const int s  = gr - (b ? s_m : 0);
        #pragma unroll
        for (int j = 0; j < 4; ++j) {
            const int col   = c0 + j * 16 + c;
            const int which = col >> 8;
            const int head  = (col >> 5) & 7;
            const int dd    = col & 31;
            const float bv  = bias[col];
            const f32x4 a   = acc[i][j];
            if (which < 2) {
                const float qs = (which == 0) ? QK_SCALE : 1.0f;
                _Float16* dst;
                int base;
                if (m < 2) {
                    dst  = wsh + (which == 0 ? QM_H : KM_H);
                    base = ((b * NHEADS + head) * SM_TOT + (s + m * S_MAIN)) * HD + dd;
                } else {
                    dst  = wsh + (which == 0 ? QA_H : KA_H);
                    base = ((((m - 2) * BS + b) * NHEADS + head) * S_AUX + s) * HD + dd;
                }
                dst[base + 0 * HD] = (_Float16)((a[0] + bv) * qs);
                dst[base + 1 * HD] = (_Float16)((a[1] + bv) * qs);
                dst[base + 2 * HD] = (_Float16)((a[2] + bv) * qs);
                dst[base + 3 * HD] = (_Float16)((a[3] + bv) * qs);
            } else {
                _Float16* dst;
                int base;
                if (m < 2) {
                    dst  = wsh + VMT_H;
                    base = ((b * NHEADS + head) * HD + dd) * SM_TOT + (s + m * S_MAIN);
                } else {
                    dst  = wsh + VAT_H;
                    base = ((((m - 2) * BS + b) * NHEADS + head) * HD + dd) * S_AUX + s;
                }
                f16x4 hv;
                hv[0] = (_Float16)(a[0] + bv);
                hv[1] = (_Float16)(a[1] + bv);
                hv[2] = (_Float16)(a[2] + bv);
                hv[3] = (_Float16)(a[3] + bv);
                *(f16x4*)(dst + base) = hv;
            }
        }
    }
}

// ---------------------------------------------------------------------------
// Kernel 2: flash attention, LDS-shared K/V (R13 structure). NEW: K tile is
// chunk-XOR swizzled (source side: chunk (l&3)^((row>>3)&3); read side:
// koff = row*HD + (g^(c>>2))*8) -> K ds_read_b128 now 2-way max (free).
// V swizzle unchanged. Compute body identical to R13.
// ---------------------------------------------------------------------------
__global__ __launch_bounds__(256) void attn_mfma_kernel(
    const _Float16* __restrict__ wsh, float* __restrict__ wsf)
{
    __shared__ _Float16 kbuf[2][64 * 32];   // [buf][key][d], chunk-swizzled
    __shared__ _Float16 vbuf[2][32 * 64];   // [buf][d][key], chunk-swizzled

    const int wid  = threadIdx.x >> 6;
    const int lane = threadIdx.x & 63;
    const int g    = lane >> 4;
    const int c    = lane & 15;

    const int bid = blockIdx.x;             // [0, 1152)

    const _Float16 *qp, *kp0, *vt0, *kp1, *vt1;
    int n0, n1, vs1, orow0, ocol, half;

    if (bid < 384) {                        // aux: 32 (mod,b,h) x 6 qt x 2 half
        const int mbhg = bid / 12;
        const int mod  = mbhg >> 4;
        const int b    = (mbhg >> 3) & 1;
        const int h    = mbhg & 7;
        const int t    = bid % 12;
        const int qt   = t >> 1;
        half = t & 1;
        const int q0   = qt * 128 + wid * 32;
        const int mbh  = (mod * BS + b) * NHEADS + h;
        const int bh   = b * NHEADS + h;
        qp = wsh + QA_H + (mbh * S_AUX + q0) * HD;
        if (half == 0) {
            kp0 = wsh + KM_H  + bh * SM_TOT * HD;
            vt0 = wsh + VMT_H + bh * HD * SM_TOT;
            n0  = 1920;
            kp1 = nullptr; vt1 = nullptr; n1 = 0; vs1 = 0;
        } else {
            kp0 = wsh + KM_H  + (bh * SM_TOT + 1920) * HD;
            vt0 = wsh + VMT_H + bh * HD * SM_TOT + 1920;
            n0  = 1152;
            kp1 = wsh + KA_H  + mbh * S_AUX * HD;
            vt1 = wsh + VAT_H + mbh * HD * S_AUX;
            n1  = S_AUX; vs1 = S_AUX;
        }
        orow0 = b * S_TOT + SM_TOT + mod * S_AUX + q0;
        ocol  = h * HD;
    } else {                                // main: 16 bh x 24 qt x 2 half
        const int idx = bid - 384;
        const int bh  = idx / 48;
        const int t   = idx % 48;
        const int qt  = t >> 1;
        half = t & 1;
        const int q0  = qt * 128 + wid * 32;
        const int b = bh >> 3, h = bh & 7;
        const int ks = half * 1536;
        qp  = wsh + QM_H  + (bh * SM_TOT + q0) * HD;
        kp0 = wsh + KM_H  + (bh * SM_TOT + ks) * HD;
        vt0 = wsh + VMT_H + bh * HD * SM_TOT + ks;
        n0  = 1536;
        kp1 = nullptr; vt1 = nullptr; n1 = 0; vs1 = 0;
        orow0 = b * S_TOT + q0;
        ocol  = h * HD;
    }

    const f16x8 qfA = *(const f16x8*)(qp + c * HD + g * 8);
    const f16x8 qfB = *(const f16x8*)(qp + (16 + c) * HD + g * 8);

    // K swizzled read offsets: row pc, lds chunk g^(c>>2)
    const int pc    = ((c >> 2) << 3) + (c & 3);
    const int kchr  = (g ^ (c >> 2)) << 3;          // swizzled chunk (halves)
    const int koff0 = pc * HD + kchr;
    const int koff1 = (pc + 4) * HD + kchr;

    // K staging geometry: lane stages row krow, lds chunk l&3, source chunk XOR'd
    const int krow  = wid * 16 + (lane >> 2);
    const int kchg  = ((lane & 3) ^ ((krow >> 3) & 3)) << 3;  // src chunk (halves)

    // V staging geometry (unchanged)
    const int srow = wid * 8 + (lane >> 3);
    const int jl   = lane & 7;
    const int vswz = (jl ^ (srow & 7)) << 3;
    const int vr0 = ((g     ^ (c & 7)) << 3);
    const int vr1 = (((g+4) ^ (c & 7)) << 3);

    f16x8 ones;
    #pragma unroll
    for (int i = 0; i < 8; ++i) ones[i] = (_Float16)1.0f;

    f32x4 otA0 = {0.f, 0.f, 0.f, 0.f}, otA1 = {0.f, 0.f, 0.f, 0.f};
    f32x4 otB0 = {0.f, 0.f, 0.f, 0.f}, otB1 = {0.f, 0.f, 0.f, 0.f};
    f32x4 ltA  = {0.f, 0.f, 0.f, 0.f}, ltB  = {0.f, 0.f, 0.f, 0.f};

    int cur = 0;

    #pragma unroll 1
    for (int seg = 0; seg < 2; ++seg) {
        const _Float16* kp_ = seg ? kp1 : kp0;
        const _Float16* vt_ = seg ? vt1 : vt0;
        const int n  = seg ? n1  : n0;
        const int vs = seg ? vs1 : SM_TOT;
        if (n == 0) break;

        #define STAGE(BI, K0)                                                  \
            {                                                                  \
                const _Float16* ks_ = kp_ + (K0 + krow) * HD + kchg;           \
                GLOAD_LDS(ks_, &kbuf[BI][wid * 512]);                          \
                const _Float16* vs_ = vt_ + (K0) + srow * vs + vswz;           \
                GLOAD_LDS(vs_, &vbuf[BI][wid * 512]);                          \
            }

        #define COMPUTE_TILE(BI)                                               \
            {                                                                  \
                const _Float16* kb_ = &kbuf[BI][0];                            \
                const _Float16* vb_ = &vbuf[BI][0];                            \
                const f16x8 kf0 = *(const f16x8*)(kb_ + koff0);                \
                const f16x8 kf1 = *(const f16x8*)(kb_ + koff1);                \
                const f16x8 kf2 = *(const f16x8*)(kb_ + 32 * HD + koff0);      \
                const f16x8 kf3 = *(const f16x8*)(kb_ + 32 * HD + koff1);      \
                const f16x8 va0 = *(const f16x8*)(vb_ + c * 64 + vr0);         \
                const f16x8 va1 = *(const f16x8*)(vb_ + (16 + c) * 64 + vr0);  \
                const f16x8 vb0 = *(const f16x8*)(vb_ + c * 64 + vr1);         \
                const f16x8 vb1 = *(const f16x8*)(vb_ + (16 + c) * 64 + vr1);  \
                f32x4 sA0 = __builtin_amdgcn_mfma_f32_16x16x32_f16(            \
                    kf0, qfA, (f32x4){0.f, 0.f, 0.f, 0.f}, 0, 0, 0);           \
                f32x4 sA1 = __builtin_amdgcn_mfma_f32_16x16x32_f16(            \
                    kf1, qfA, (f32x4){0.f, 0.f, 0.f, 0.f}, 0, 0, 0);           \
                f32x4 sA2 = __builtin_amdgcn_mfma_f32_16x16x32_f16(            \
                    kf2, qfA, (f32x4){0.f, 0.f, 0.f, 0.f}, 0, 0, 0);           \
                f32x4 sA3 = __builtin_amdgcn_mfma_f32_16x16x32_f16(            \
                    kf3, qfA, (f32x4){0.f, 0.f, 0.f, 0.f}, 0, 0, 0);           \
                f32x4 sB0 = __builtin_amdgcn_mfma_f32_16x16x32_f16(            \
                    kf0, qfB, (f32x4){0.f, 0.f, 0.f, 0.f}, 0, 0, 0);           \
                f32x4 sB1 = __builtin_amdgcn_mfma_f32_16x16x32_f16(            \
                    kf1, qfB, (f32x4){0.f, 0.f, 0.f, 0.f}, 0, 0, 0);           \
                f32x4 sB2 = __builtin_amdgcn_mfma_f32_16x16x32_f16(            \
                    kf2, qfB, (f32x4){0.f, 0.f, 0.f, 0.f}, 0, 0, 0);           \
                f32x4 sB3 = __builtin_amdgcn_mfma_f32_16x16x32_f16(            \
                    kf3, qfB, (f32x4){0.f, 0.f, 0.f, 0.f}, 0, 0, 0);           \
                float pA0[4], pA1[4], pA2[4], pA3[4];                          \
                float pB0[4], pB1[4], pB2[4], pB3[4];                          \
                _Pragma("unroll")                                              \
                for (int r = 0; r < 4; ++r) {                                  \
                    pA0[r] = __builtin_amdgcn_exp2f(sA0[r]);                   \
                    pA1[r] = __builtin_amdgcn_exp2f(sA1[r]);                   \
                    pA2[r] = __builtin_amdgcn_exp2f(sA2[r]);                   \
                    pA3[r] = __builtin_amdgcn_exp2f(sA3[r]);                   \
                    pB0[r] = __builtin_amdgcn_exp2f(sB0[r]);                   \
                    pB1[r] = __builtin_amdgcn_exp2f(sB1[r]);                   \
                    pB2[r] = __builtin_amdgcn_exp2f(sB2[r]);                   \
                    pB3[r] = __builtin_amdgcn_exp2f(sB3[r]);                   \
                }                                                              \
                f16x8 pbA0, pbA1, pbB0, pbB1;                                  \
                _Pragma("unroll")                                              \
                for (int r = 0; r < 4; ++r) {                                  \
                    pbA0[r]     = (_Float16)pA0[r];                            \
                    pbA0[r + 4] = (_Float16)pA1[r];                            \
                    pbA1[r]     = (_Float16)pA2[r];                            \
                    pbA1[r + 4] = (_Float16)pA3[r];                            \
                    pbB0[r]     = (_Float16)pB0[r];                            \
                    pbB0[r + 4] = (_Float16)pB1[r];                            \
                    pbB1[r]     = (_Float16)pB2[r];                            \
                    pbB1[r + 4] = (_Float16)pB3[r];                            \
                }                                                              \
                ltA = __builtin_amdgcn_mfma_f32_16x16x32_f16(ones, pbA0, ltA, 0, 0, 0); \
                ltA = __builtin_amdgcn_mfma_f32_16x16x32_f16(ones, pbA1, ltA, 0, 0, 0); \
                ltB = __builtin_amdgcn_mfma_f32_16x16x32_f16(ones, pbB0, ltB, 0, 0, 0); \
                ltB = __builtin_amdgcn_mfma_f32_16x16x32_f16(ones, pbB1, ltB, 0, 0, 0); \
                otA0 = __builtin_amdgcn_mfma_f32_16x16x32_f16(va0, pbA0, otA0, 0, 0, 0); \
                otA1 = __builtin_amdgcn_mfma_f32_16x16x32_f16(va1, pbA0, otA1, 0, 0, 0); \
                otB0 = __builtin_amdgcn_mfma_f32_16x16x32_f16(va0, pbB0, otB0, 0, 0, 0); \
                otB1 = __builtin_amdgcn_mfma_f32_16x16x32_f16(va1, pbB0, otB1, 0, 0, 0); \
                otA0 = __builtin_amdgcn_mfma_f32_16x16x32_f16(vb0, pbA1, otA0, 0, 0, 0); \
                otA1 = __builtin_amdgcn_mfma_f32_16x16x32_f16(vb1, pbA1, otA1, 0, 0, 0); \
                otB0 = __builtin_amdgcn_mfma_f32_16x16x32_f16(vb0, pbB1, otB0, 0, 0, 0); \
                otB1 = __builtin_amdgcn_mfma_f32_16x16x32_f16(vb1, pbB1, otB1, 0, 0, 0); \
            }

        STAGE(cur, 0);
        __syncthreads();

        #pragma unroll 1
        for (int k0 = 0; k0 < n; k0 += 64) {
            if (k0 + 64 < n)
                STAGE(cur ^ 1, k0 + 64);
            COMPUTE_TILE(cur);
            __syncthreads();
            cur ^= 1;
        }

        #undef STAGE
        #undef COMPUTE_TILE
    }

    float* aoBase = wsf + (half ? AO1_F : AO0_F);
    float* lBase  = wsf + (half ? L1_F  : L0_F);

    float* aoA = aoBase + (orow0 + c) * DIM + ocol;
    float* aoB = aoBase + (orow0 + 16 + c) * DIM + ocol;
    float4 w0, w1, w2, w3;
    w0.x = otA0[0]; w0.y = otA0[1]; w0.z = otA0[2]; w0.w = otA0[3];
    w1.x = otA1[0]; w1.y = otA1[1]; w1.z = otA1[2]; w1.w = otA1[3];
    w2.x = otB0[0]; w2.y = otB0[1]; w2.z = otB0[2]; w2.w = otB0[3];
    w3.x = otB1[0]; w3.y = otB1[1]; w3.z = otB1[2]; w3.w = otB1[3];
    *(float4*)(aoA + 4 * g)      = w0;
    *(float4*)(aoA + 16 + 4 * g) = w1;
    *(float4*)(aoB + 4 * g)      = w2;
    *(float4*)(aoB + 16 + 4 * g) = w3;

    if (g == 0) {
        lBase[orow0 + c]      = ltA[0];
        lBase[orow0 + 16 + c] = ltB[0];
    }
}

// ---------------------------------------------------------------------------
// Kernel 3: output projection. A-staging keeps fused combine+normalize (fp32);
// B-staging now f16x8 vector copies from pre-converted Wt2.
// ---------------------------------------------------------------------------
__global__ __launch_bounds__(256) void proj_mfma_kernel(
    const float* __restrict__ wsf, const _Float16* __restrict__ wsh_ro,
    const float* __restrict__ bproj, float* __restrict__ out)
{
    const int ct = blockIdx.x;
    const int rt = blockIdx.y;
    const int r0 = rt * 128, c0 = ct * 64;
    const int seq = r0 % S_TOT;
    const int mod = (seq < S_MAIN) ? 0 : (seq < SM_TOT) ? 1
                  : (seq < SM_TOT + S_AUX) ? 2 : 3;
    const _Float16* Wt = wsh_ro + WT2_H + mod * (DIM * DIM);
    const float* bias  = bproj + mod * DIM;
    const float* A0    = wsf + AO0_F;
    const float* A1    = wsf + AO1_F;
    const float* L0p   = wsf + L0_F;
    const float* L1p   = wsf + L1_F;

    __shared__ _Float16 As[128][40];
    __shared__ _Float16 Bs[64][40];
    __shared__ float Linv[128];

    const int t    = threadIdx.x;
    const int wid  = t >> 6;
    const int lane = t & 63;
    const int g    = lane >> 4;
    const int c    = lane & 15;

    if (t < 128) Linv[t] = 1.0f / (L0p[r0 + t] + L1p[r0 + t]);
    __syncthreads();

    const int arow = t >> 1;
    const int ak   = (t & 1) << 4;
    const int bcol = t & 63;
    const int bkg  = t >> 6;
    const int bsg  = bkg ^ ((bcol >> 3) & 3);
    const float linv_r = Linv[arow];

    f32x4 acc[2][4];
    #pragma unroll
    for (int i = 0; i < 2; ++i)
        #pragma unroll
        for (int j = 0; j < 4; ++j)
            acc[i][j] = (f32x4){0.f, 0.f, 0.f, 0.f};

    const float* pa0 = A0 + (r0 + arow) * DIM + ak;
    const float* pa1 = A1 + (r0 + arow) * DIM + ak;
    const _Float16* wp = Wt + (c0 + bcol) * DIM;

    for (int kk = 0; kk < DIM; kk += 32) {
        {
            const float4 u0 = *(const float4*)(pa0 + kk + 0);
            const float4 u1 = *(const float4*)(pa0 + kk + 4);
            const float4 u2 = *(const float4*)(pa0 + kk + 8);
            const float4 u3 = *(const float4*)(pa0 + kk + 12);
            const float4 v0 = *(const float4*)(pa1 + kk + 0);
            const float4 v1 = *(const float4*)(pa1 + kk + 4);
            const float4 v2 = *(const float4*)(pa1 + kk + 8);
            const float4 v3 = *(const float4*)(pa1 + kk + 12);
            f16x8 h0, h1;
            h0[0] = (_Float16)((u0.x + v0.x) * linv_r);
            h0[1] = (_Float16)((u0.y + v0.y) * linv_r);
            h0[2] = (_Float16)((u0.z + v0.z) * linv_r);
            h0[3] = (_Float16)((u0.w + v0.w) * linv_r);
            h0[4] = (_Float16)((u1.x + v1.x) * linv_r);
            h0[5] = (_Float16)((u1.y + v1.y) * linv_r);
            h0[6] = (_Float16)((u1.z + v1.z) * linv_r);
            h0[7] = (_Float16)((u1.w + v1.w) * linv_r);
            h1[0] = (_Float16)((u2.x + v2.x) * linv_r);
            h1[1] = (_Float16)((u2.y + v2.y) * linv_r);
            h1[2] = (_Float16)((u2.z + v2.z) * linv_r);
            h1[3] = (_Float16)((u2.w + v2.w) * linv_r);
            h1[4] = (_Float16)((u3.x + v3.x) * linv_r);
            h1[5] = (_Float16)((u3.y + v3.y) * linv_r);
            h1[6] = (_Float16)((u3.z + v3.z) * linv_r);
            h1[7] = (_Float16)((u3.w + v3.w) * linv_r);
            *(f16x8*)&As[arow][ak]     = h0;
            *(f16x8*)&As[arow][ak + 8] = h1;
        }
        {
            const f16x8 hb = *(const f16x8*)(wp + kk + bkg * 8);
            *(f16x8*)&Bs[bcol][bsg << 3] = hb;
        }
        __syncthreads();
        const f16x8 af0 = *(const f16x8*)&As[wid * 32 + c][g * 8];
        const f16x8 af1 = *(const f16x8*)&As[wid * 32 + 16 + c][g * 8];
        #pragma unroll
        for (int j = 0; j < 4; ++j) {
            const int bc = j * 16 + c;
            const int gg = g ^ ((bc >> 3) & 3);
            const f16x8 bf = *(const f16x8*)&Bs[bc][gg * 8];
            acc[0][j] = __builtin_amdgcn_mfma_f32_16x16x32_f16(af0, bf, acc[0][j], 0, 0, 0);
            acc[1][j] = __builtin_amdgcn_mfma_f32_16x16x32_f16(af1, bf, acc[1][j], 0, 0, 0);
        }
        __syncthreads();
    }

    #pragma unroll
    for (int i = 0; i < 2; ++i) {
        const int gr = r0 + wid * 32 + i * 16 + 4 * g;
        #pragma unroll
        for (int j = 0; j < 4; ++j) {
            const int col  = c0 + j * 16 + c;
            const float bv = bias[col];
            const f32x4 a  = acc[i][j];
            out[(gr + 0) * DIM + col] = a[0] + bv;
            out[(gr + 1) * DIM + col] = a[1] + bv;
            out[(gr + 2) * DIM + col] = a[2] + bv;
            out[(gr + 3) * DIM + col] = a[3] + bv;
        }
    }
}

extern "C" void kernel_launch(void* const* d_in, const int* in_sizes, int n_in,
                              void* d_out, int out_size, void* d_ws, size_t ws_size,
                              hipStream_t stream)
{
    const float* x0    = (const float*)d_in[0];
    const float* x1    = (const float*)d_in[1];
    const float* x2    = (const float*)d_in[2];
    const float* x3    = (const float*)d_in[3];
    const float* Wqkv  = (const float*)d_in[4];
    const float* bqkv  = (const float*)d_in[5];
    const float* Wproj = (const float*)d_in[6];
    const float* bproj = (const float*)d_in[7];
    _Float16* wsh = (_Float16*)d_ws;
    float*    wsf = (float*)d_ws;
    float*    out = (float*)d_out;

    // 0) pre-convert x -> fp16, W -> fp16 transposed
    convert_kernel<<<dim3(1216), 256, 0, stream>>>(
        x0, x1, x2, x3, Wqkv, Wproj, wsh);

    // 1) QKV projection: 12 col-tiles x 24 row-tiles(128) x 4 mods
    qkv_mfma_kernel<<<dim3(12, 24, 4), 256, 0, stream>>>(wsh, bqkv, wsh);

    // 2) attention: 1152 blocks x 4 waves, LDS-shared K/V
    attn_mfma_kernel<<<dim3(1152), 256, 0, stream>>>(wsh, wsf);

    // 3) output projection (+ partial combine + normalize): 4 x 72 tiles
    proj_mfma_kernel<<<dim3(4, 72), 256, 0, stream>>>(wsf, wsh, bproj, out);
}

// Round 15
// 91.669 us; speedup vs baseline: 1.1098x; 1.1098x over previous
//
#include <hip/hip_runtime.h>
#include <hip/hip_bf16.h>
#include <math.h>

#define BS 2
#define NHEADS 8
#define HD 32
#define DIM 256
#define W3 768          // 3*DIM
#define S_MAIN 1536
#define S_AUX 768
#define SM_TOT 3072
#define S_TOT 4608

typedef _Float16 f16x8 __attribute__((ext_vector_type(8)));
typedef _Float16 f16x4 __attribute__((ext_vector_type(4)));
typedef float    f32x4 __attribute__((ext_vector_type(4)));

// 1/sqrt(32) * log2(e): Q pre-scaled so softmax runs in exp2 domain
#define QK_SCALE 0.25503491f

// ---- workspace layout ----
#define QM_H  0
#define KM_H  1572864
#define VMT_H 3145728
#define QA_H  4718592
#define KA_H  5505024
#define VAT_H 6291456
#define AO0_F 3538944
#define AO1_F 5898240
#define L0_F  8257536
#define L1_F  8266752

// async global->LDS, 16B per lane, dest = wave-uniform base + lane*16
#define GLOAD_LDS(SRC, DST)                                                    \
    __builtin_amdgcn_global_load_lds(                                          \
        (const __attribute__((address_space(1))) void*)(SRC),                  \
        (__attribute__((address_space(3))) void*)(DST), 16, 0, 0)

// ---------------------------------------------------------------------------
// Kernel 1: QKV projection, fp16 MFMA (R13 version — in-kernel cvt).
// ---------------------------------------------------------------------------
__global__ __launch_bounds__(256) void qkv_mfma_kernel(
    const float* __restrict__ x0, const float* __restrict__ x1,
    const float* __restrict__ x2, const float* __restrict__ x3,
    const float* __restrict__ Wqkv, const float* __restrict__ bqkv,
    _Float16* __restrict__ wsh)
{
    const int m  = blockIdx.z;
    const int rt = blockIdx.y;
    const int ct = blockIdx.x;
    const int s_m   = (m < 2) ? S_MAIN : S_AUX;
    const int nrows = BS * s_m;
    const int r0 = rt * 128;
    if (r0 >= nrows) return;

    const float* x    = (m == 0) ? x0 : (m == 1) ? x1 : (m == 2) ? x2 : x3;
    const float* W    = Wqkv + m * (DIM * W3);
    const float* bias = bqkv + m * W3;

    __shared__ _Float16 As[128][40];
    __shared__ _Float16 Bs[64][40];

    const int t    = threadIdx.x;
    const int wid  = t >> 6;
    const int lane = t & 63;
    const int g    = lane >> 4;
    const int c    = lane & 15;
    const int c0   = ct * 64;

    const int arow = t >> 1;
    const int ak   = (t & 1) << 4;
    const int bcol = t & 63;
    const int bkg  = t >> 6;
    const int bsg  = bkg ^ ((bcol >> 3) & 3);

    f32x4 acc[2][4];
    #pragma unroll
    for (int i = 0; i < 2; ++i)
        #pragma unroll
        for (int j = 0; j < 4; ++j)
            acc[i][j] = (f32x4){0.f, 0.f, 0.f, 0.f};

    const float* xp = x + (r0 + arow) * DIM + ak;
    const float* wp = W + (bkg * 8) * W3 + c0 + bcol;

    for (int kk = 0; kk < DIM; kk += 32) {
        {
            const float4 u0 = *(const float4*)(xp + kk + 0);
            const float4 u1 = *(const float4*)(xp + kk + 4);
            const float4 u2 = *(const float4*)(xp + kk + 8);
            const float4 u3 = *(const float4*)(xp + kk + 12);
            f16x8 h0, h1;
            h0[0] = (_Float16)u0.x; h0[1] = (_Float16)u0.y;
            h0[2] = (_Float16)u0.z; h0[3] = (_Float16)u0.w;
            h0[4] = (_Float16)u1.x; h0[5] = (_Float16)u1.y;
            h0[6] = (_Float16)u1.z; h0[7] = (_Float16)u1.w;
            h1[0] = (_Float16)u2.x; h1[1] = (_Float16)u2.y;
            h1[2] = (_Float16)u2.z; h1[3] = (_Float16)u2.w;
            h1[4] = (_Float16)u3.x; h1[5] = (_Float16)u3.y;
            h1[6] = (_Float16)u3.z; h1[7] = (_Float16)u3.w;
            *(f16x8*)&As[arow][ak]     = h0;
            *(f16x8*)&As[arow][ak + 8] = h1;
        }
        {
            const float* wq = wp + kk * W3;
            f16x8 hb;
            hb[0] = (_Float16)wq[0 * W3]; hb[1] = (_Float16)wq[1 * W3];
            hb[2] = (_Float16)wq[2 * W3]; hb[3] = (_Float16)wq[3 * W3];
            hb[4] = (_Float16)wq[4 * W3]; hb[5] = (_Float16)wq[5 * W3];
            hb[6] = (_Float16)wq[6 * W3]; hb[7] = (_Float16)wq[7 * W3];
            *(f16x8*)&Bs[bcol][bsg << 3] = hb;
        }
        __syncthreads();
        const f16x8 af0 = *(const f16x8*)&As[wid * 32 + c][g * 8];
        const f16x8 af1 = *(const f16x8*)&As[wid * 32 + 16 + c][g * 8];
        #pragma unroll
        for (int j = 0; j < 4; ++j) {
            const int bc = j * 16 + c;
            const int gg = g ^ ((bc >> 3) & 3);
            const f16x8 bf = *(const f16x8*)&Bs[bc][gg * 8];
            acc[0][j] = __builtin_amdgcn_mfma_f32_16x16x32_f16(af0, bf, acc[0][j], 0, 0, 0);
            acc[1][j] = __builtin_amdgcn_mfma_f32_16x16x32_f16(af1, bf, acc[1][j], 0, 0, 0);
        }
        __syncthreads();
    }

    #pragma unroll
    for (int i = 0; i < 2; ++i) {
        const int gr = r0 + wid * 32 + i * 16 + 4 * g;
        const int b  = (gr >= s_m) ? 1 : 0;
        const int s  = gr - (b ? s_m : 0);
        #pragma unroll
        for (int j = 0; j < 4; ++j) {
            const int col   = c0 + j * 16 + c;
            const int which = col >> 8;
            const int head  = (col >> 5) & 7;
            const int dd    = col & 31;
            const float bv  = bias[col];
            const f32x4 a   = acc[i][j];
            if (which < 2) {
                const float qs = (which == 0) ? QK_SCALE : 1.0f;
                _Float16* dst;
                int base;
                if (m < 2) {
                    dst  = wsh + (which == 0 ? QM_H : KM_H);
                    base = ((b * NHEADS + head) * SM_TOT + (s + m * S_MAIN)) * HD + dd;
                } else {
                    dst  = wsh + (which == 0 ? QA_H : KA_H);
                    base = ((((m - 2) * BS + b) * NHEADS + head) * S_AUX + s) * HD + dd;
                }
                dst[base + 0 * HD] = (_Float16)((a[0] + bv) * qs);
                dst[base + 1 * HD] = (_Float16)((a[1] + bv) * qs);
                dst[base + 2 * HD] = (_Float16)((a[2] + bv) * qs);
                dst[base + 3 * HD] = (_Float16)((a[3] + bv) * qs);
            } else {
                _Float16* dst;
                int base;
                if (m < 2) {
                    dst  = wsh + VMT_H;
                    base = ((b * NHEADS + head) * HD + dd) * SM_TOT + (s + m * S_MAIN);
                } else {
                    dst  = wsh + VAT_H;
                    base = ((((m - 2) * BS + b) * NHEADS + head) * HD + dd) * S_AUX + s;
                }
                f16x4 hv;
                hv[0] = (_Float16)(a[0] + bv);
                hv[1] = (_Float16)(a[1] + bv);
                hv[2] = (_Float16)(a[2] + bv);
                hv[3] = (_Float16)(a[3] + bv);
                *(f16x4*)(dst + base) = hv;
            }
        }
    }
}

// ---------------------------------------------------------------------------
// Kernel 2: flash attention, LDS-shared K/V. CHANGE vs R13/R14: 128-key
// staging tiles (two 64-key sub-tiles, geometry identical to the verified
// 64-key layout) -> HALF the barriers, 2x compute per vmcnt-drain (~700 cyc
// covers contended L2 latency). LDS 32KB, still 5 blocks/CU.
// All segment lengths (1920/1152/1536/768) divide 128 -> no tail.
// Compute body identical to R13/R14 (K chunk-swizzle retained).
// ---------------------------------------------------------------------------
__global__ __launch_bounds__(256) void attn_mfma_kernel(
    const _Float16* __restrict__ wsh, float* __restrict__ wsf)
{
    __shared__ _Float16 kbuf[2][2][64 * 32];   // [buf][sub][key][d], swizzled
    __shared__ _Float16 vbuf[2][2][32 * 64];   // [buf][sub][d][key], swizzled

    const int wid  = threadIdx.x >> 6;
    const int lane = threadIdx.x & 63;
    const int g    = lane >> 4;
    const int c    = lane & 15;

    const int bid = blockIdx.x;             // [0, 1152)

    const _Float16 *qp, *kp0, *vt0, *kp1, *vt1;
    int n0, n1, vs1, orow0, ocol, half;

    if (bid < 384) {                        // aux: 32 (mod,b,h) x 6 qt x 2 half
        const int mbhg = bid / 12;
        const int mod  = mbhg >> 4;
        const int b    = (mbhg >> 3) & 1;
        const int h    = mbhg & 7;
        const int t    = bid % 12;
        const int qt   = t >> 1;
        half = t & 1;
        const int q0   = qt * 128 + wid * 32;
        const int mbh  = (mod * BS + b) * NHEADS + h;
        const int bh   = b * NHEADS + h;
        qp = wsh + QA_H + (mbh * S_AUX + q0) * HD;
        if (half == 0) {
            kp0 = wsh + KM_H  + bh * SM_TOT * HD;
            vt0 = wsh + VMT_H + bh * HD * SM_TOT;
            n0  = 1920;
            kp1 = nullptr; vt1 = nullptr; n1 = 0; vs1 = 0;
        } else {
            kp0 = wsh + KM_H  + (bh * SM_TOT + 1920) * HD;
            vt0 = wsh + VMT_H + bh * HD * SM_TOT + 1920;
            n0  = 1152;
            kp1 = wsh + KA_H  + mbh * S_AUX * HD;
            vt1 = wsh + VAT_H + mbh * HD * S_AUX;
            n1  = S_AUX; vs1 = S_AUX;
        }
        orow0 = b * S_TOT + SM_TOT + mod * S_AUX + q0;
        ocol  = h * HD;
    } else {                                // main: 16 bh x 24 qt x 2 half
        const int idx = bid - 384;
        const int bh  = idx / 48;
        const int t   = idx % 48;
        const int qt  = t >> 1;
        half = t & 1;
        const int q0  = qt * 128 + wid * 32;
        const int b = bh >> 3, h = bh & 7;
        const int ks = half * 1536;
        qp  = wsh + QM_H  + (bh * SM_TOT + q0) * HD;
        kp0 = wsh + KM_H  + (bh * SM_TOT + ks) * HD;
        vt0 = wsh + VMT_H + bh * HD * SM_TOT + ks;
        n0  = 1536;
        kp1 = nullptr; vt1 = nullptr; n1 = 0; vs1 = 0;
        orow0 = b * S_TOT + q0;
        ocol  = h * HD;
    }

    const f16x8 qfA = *(const f16x8*)(qp + c * HD + g * 8);
    const f16x8 qfB = *(const f16x8*)(qp + (16 + c) * HD + g * 8);

    // K swizzled read offsets: row pc, lds chunk g^(c>>2)
    const int pc    = ((c >> 2) << 3) + (c & 3);
    const int kchr  = (g ^ (c >> 2)) << 3;
    const int koff0 = pc * HD + kchr;
    const int koff1 = (pc + 4) * HD + kchr;

    // K staging geometry (per 64-key sub-tile): lane stages row krow
    const int krow  = wid * 16 + (lane >> 2);
    const int kchg  = ((lane & 3) ^ ((krow >> 3) & 3)) << 3;

    // V staging geometry (per 64-key sub-tile)
    const int srow = wid * 8 + (lane >> 3);
    const int jl   = lane & 7;
    const int vswz = (jl ^ (srow & 7)) << 3;
    const int vr0 = ((g     ^ (c & 7)) << 3);
    const int vr1 = (((g+4) ^ (c & 7)) << 3);

    f16x8 ones;
    #pragma unroll
    for (int i = 0; i < 8; ++i) ones[i] = (_Float16)1.0f;

    f32x4 otA0 = {0.f, 0.f, 0.f, 0.f}, otA1 = {0.f, 0.f, 0.f, 0.f};
    f32x4 otB0 = {0.f, 0.f, 0.f, 0.f}, otB1 = {0.f, 0.f, 0.f, 0.f};
    f32x4 ltA  = {0.f, 0.f, 0.f, 0.f}, ltB  = {0.f, 0.f, 0.f, 0.f};

    int cur = 0;

    #pragma unroll 1
    for (int seg = 0; seg < 2; ++seg) {
        const _Float16* kp_ = seg ? kp1 : kp0;
        const _Float16* vt_ = seg ? vt1 : vt0;
        const int n  = seg ? n1  : n0;
        const int vs = seg ? vs1 : SM_TOT;
        if (n == 0) break;

        // stage one 64-key sub-tile (K 4KB + V 4KB); 2 gload_lds per wave
        #define STAGE(BI, S, K0)                                               \
            {                                                                  \
                const _Float16* ks_ = kp_ + (K0 + krow) * HD + kchg;           \
                GLOAD_LDS(ks_, &kbuf[BI][S][wid * 512]);                       \
                const _Float16* vs_ = vt_ + (K0) + srow * vs + vswz;           \
                GLOAD_LDS(vs_, &vbuf[BI][S][wid * 512]);                       \
            }

        #define COMPUTE_TILE(BI, S)                                            \
            {                                                                  \
                const _Float16* kb_ = &kbuf[BI][S][0];                         \
                const _Float16* vb_ = &vbuf[BI][S][0];                         \
                const f16x8 kf0 = *(const f16x8*)(kb_ + koff0);                \
                const f16x8 kf1 = *(const f16x8*)(kb_ + koff1);                \
                const f16x8 kf2 = *(const f16x8*)(kb_ + 32 * HD + koff0);      \
                const f16x8 kf3 = *(const f16x8*)(kb_ + 32 * HD + koff1);      \
                const f16x8 va0 = *(const f16x8*)(vb_ + c * 64 + vr0);         \
                const f16x8 va1 = *(const f16x8*)(vb_ + (16 + c) * 64 + vr0);  \
                const f16x8 vb0 = *(const f16x8*)(vb_ + c * 64 + vr1);         \
                const f16x8 vb1 = *(const f16x8*)(vb_ + (16 + c) * 64 + vr1);  \
                f32x4 sA0 = __builtin_amdgcn_mfma_f32_16x16x32_f16(            \
                    kf0, qfA, (f32x4){0.f, 0.f, 0.f, 0.f}, 0, 0, 0);           \
                f32x4 sA1 = __builtin_amdgcn_mfma_f32_16x16x32_f16(            \
                    kf1, qfA, (f32x4){0.f, 0.f, 0.f, 0.f}, 0, 0, 0);           \
                f32x4 sA2 = __builtin_amdgcn_mfma_f32_16x16x32_f16(            \
                    kf2, qfA, (f32x4){0.f, 0.f, 0.f, 0.f}, 0, 0, 0);           \
                f32x4 sA3 = __builtin_amdgcn_mfma_f32_16x16x32_f16(            \
                    kf3, qfA, (f32x4){0.f, 0.f, 0.f, 0.f}, 0, 0, 0);           \
                f32x4 sB0 = __builtin_amdgcn_mfma_f32_16x16x32_f16(            \
                    kf0, qfB, (f32x4){0.f, 0.f, 0.f, 0.f}, 0, 0, 0);           \
                f32x4 sB1 = __builtin_amdgcn_mfma_f32_16x16x32_f16(            \
                    kf1, qfB, (f32x4){0.f, 0.f, 0.f, 0.f}, 0, 0, 0);           \
                f32x4 sB2 = __builtin_amdgcn_mfma_f32_16x16x32_f16(            \
                    kf2, qfB, (f32x4){0.f, 0.f, 0.f, 0.f}, 0, 0, 0);           \
                f32x4 sB3 = __builtin_amdgcn_mfma_f32_16x16x32_f16(            \
                    kf3, qfB, (f32x4){0.f, 0.f, 0.f, 0.f}, 0, 0, 0);           \
                float pA0[4], pA1[4], pA2[4], pA3[4];                          \
                float pB0[4], pB1[4], pB2[4], pB3[4];                          \
                _Pragma("unroll")                                              \
                for (int r = 0; r < 4; ++r) {                                  \
                    pA0[r] = __builtin_amdgcn_exp2f(sA0[r]);                   \
                    pA1[r] = __builtin_amdgcn_exp2f(sA1[r]);                   \
                    pA2[r] = __builtin_amdgcn_exp2f(sA2[r]);                   \
                    pA3[r] = __builtin_amdgcn_exp2f(sA3[r]);                   \
                    pB0[r] = __builtin_amdgcn_exp2f(sB0[r]);                   \
                    pB1[r] = __builtin_amdgcn_exp2f(sB1[r]);                   \
                    pB2[r] = __builtin_amdgcn_exp2f(sB2[r]);                   \
                    pB3[r] = __builtin_amdgcn_exp2f(sB3[r]);                   \
                }                                                              \
                f16x8 pbA0, pbA1, pbB0, pbB1;                                  \
                _Pragma("unroll")                                              \
                for (int r = 0; r < 4; ++r) {                                  \
                    pbA0[r]     = (_Float16)pA0[r];                            \
                    pbA0[r + 4] = (_Float16)pA1[r];                            \
                    pbA1[r]     = (_Float16)pA2[r];                            \
                    pbA1[r + 4] = (_Float16)pA3[r];                            \
                    pbB0[r]     = (_Float16)pB0[r];                            \
                    pbB0[r + 4] = (_Float16)pB1[r];                            \
                    pbB1[r]     = (_Float16)pB2[r];                            \
                    pbB1[r + 4] = (_Float16)pB3[r];                            \
                }                                                              \
                ltA = __builtin_amdgcn_mfma_f32_16x16x32_f16(ones, pbA0, ltA, 0, 0, 0); \
                ltA = __builtin_amdgcn_mfma_f32_16x16x32_f16(ones, pbA1, ltA, 0, 0, 0); \
                ltB = __builtin_amdgcn_mfma_f32_16x16x32_f16(ones, pbB0, ltB, 0, 0, 0); \
                ltB = __builtin_amdgcn_mfma_f32_16x16x32_f16(ones, pbB1, ltB, 0, 0, 0); \
                otA0 = __builtin_amdgcn_mfma_f32_16x16x32_f16(va0, pbA0, otA0, 0, 0, 0); \
                otA1 = __builtin_amdgcn_mfma_f32_16x16x32_f16(va1, pbA0, otA1, 0, 0, 0); \
                otB0 = __builtin_amdgcn_mfma_f32_16x16x32_f16(va0, pbB0, otB0, 0, 0, 0); \
                otB1 = __builtin_amdgcn_mfma_f32_16x16x32_f16(va1, pbB0, otB1, 0, 0, 0); \
                otA0 = __builtin_amdgcn_mfma_f32_16x16x32_f16(vb0, pbA1, otA0, 0, 0, 0); \
                otA1 = __builtin_amdgcn_mfma_f32_16x16x32_f16(vb1, pbA1, otA1, 0, 0, 0); \
                otB0 = __builtin_amdgcn_mfma_f32_16x16x32_f16(vb0, pbB1, otB0, 0, 0, 0); \
                otB1 = __builtin_amdgcn_mfma_f32_16x16x32_f16(vb1, pbB1, otB1, 0, 0, 0); \
            }

        STAGE(cur, 0, 0);
        STAGE(cur, 1, 64);
        __syncthreads();                    // buf[cur] (128 keys) ready

        #pragma unroll 1
        for (int k0 = 0; k0 < n; k0 += 128) {
            if (k0 + 128 < n) {
                STAGE(cur ^ 1, 0, k0 + 128);    // async prefetch next 128 keys
                STAGE(cur ^ 1, 1, k0 + 192);
            }
            COMPUTE_TILE(cur, 0);
            COMPUTE_TILE(cur, 1);
            __syncthreads();                // one drain per 128 keys
            cur ^= 1;
        }

        #undef STAGE
        #undef COMPUTE_TILE
    }

    float* aoBase = wsf + (half ? AO1_F : AO0_F);
    float* lBase  = wsf + (half ? L1_F  : L0_F);

    float* aoA = aoBase + (orow0 + c) * DIM + ocol;
    float* aoB = aoBase + (orow0 + 16 + c) * DIM + ocol;
    float4 w0, w1, w2, w3;
    w0.x = otA0[0]; w0.y = otA0[1]; w0.z = otA0[2]; w0.w = otA0[3];
    w1.x = otA1[0]; w1.y = otA1[1]; w1.z = otA1[2]; w1.w = otA1[3];
    w2.x = otB0[0]; w2.y = otB0[1]; w2.z = otB0[2]; w2.w = otB0[3];
    w3.x = otB1[0]; w3.y = otB1[1]; w3.z = otB1[2]; w3.w = otB1[3];
    *(float4*)(aoA + 4 * g)      = w0;
    *(float4*)(aoA + 16 + 4 * g) = w1;
    *(float4*)(aoB + 4 * g)      = w2;
    *(float4*)(aoB + 16 + 4 * g) = w3;

    if (g == 0) {
        lBase[orow0 + c]      = ltA[0];
        lBase[orow0 + 16 + c] = ltB[0];
    }
}

// ---------------------------------------------------------------------------
// Kernel 3: output projection, fp16 MFMA, fused partial-combine + softmax
// normalization in the A-staging (R13 version — in-kernel W cvt).
// ---------------------------------------------------------------------------
__global__ __launch_bounds__(256) void proj_mfma_kernel(
    const float* __restrict__ wsf, const float* __restrict__ Wproj,
    const float* __restrict__ bproj, float* __restrict__ out)
{
    const int ct = blockIdx.x;
    const int rt = blockIdx.y;
    const int r0 = rt * 128, c0 = ct * 64;
    const int seq = r0 % S_TOT;
    const int mod = (seq < S_MAIN) ? 0 : (seq < SM_TOT) ? 1
                  : (seq < SM_TOT + S_AUX) ? 2 : 3;
    const float* W    = Wproj + mod * DIM * DIM;
    const float* bias = bproj + mod * DIM;
    const float* A0   = wsf + AO0_F;
    const float* A1   = wsf + AO1_F;
    const float* L0p  = wsf + L0_F;
    const float* L1p  = wsf + L1_F;

    __shared__ _Float16 As[128][40];
    __shared__ _Float16 Bs[64][40];
    __shared__ float Linv[128];

    const int t    = threadIdx.x;
    const int wid  = t >> 6;
    const int lane = t & 63;
    const int g    = lane >> 4;
    const int c    = lane & 15;

    if (t < 128) Linv[t] = 1.0f / (L0p[r0 + t] + L1p[r0 + t]);
    __syncthreads();

    const int arow = t >> 1;
    const int ak   = (t & 1) << 4;
    const int bcol = t & 63;
    const int bkg  = t >> 6;
    const int bsg  = bkg ^ ((bcol >> 3) & 3);
    const float linv_r = Linv[arow];

    f32x4 acc[2][4];
    #pragma unroll
    for (int i = 0; i < 2; ++i)
        #pragma unroll
        for (int j = 0; j < 4; ++j)
            acc[i][j] = (f32x4){0.f, 0.f, 0.f, 0.f};

    const float* pa0 = A0 + (r0 + arow) * DIM + ak;
    const float* pa1 = A1 + (r0 + arow) * DIM + ak;
    const float* wp  = W + (bkg * 8) * DIM + c0 + bcol;

    for (int kk = 0; kk < DIM; kk += 32) {
        {
            const float4 u0 = *(const float4*)(pa0 + kk + 0);
            const float4 u1 = *(const float4*)(pa0 + kk + 4);
            const float4 u2 = *(const float4*)(pa0 + kk + 8);
            const float4 u3 = *(const float4*)(pa0 + kk + 12);
            const float4 v0 = *(const float4*)(pa1 + kk + 0);
            const float4 v1 = *(const float4*)(pa1 + kk + 4);
            const float4 v2 = *(const float4*)(pa1 + kk + 8);
            const float4 v3 = *(const float4*)(pa1 + kk + 12);
            f16x8 h0, h1;
            h0[0] = (_Float16)((u0.x + v0.x) * linv_r);
            h0[1] = (_Float16)((u0.y + v0.y) * linv_r);
            h0[2] = (_Float16)((u0.z + v0.z) * linv_r);
            h0[3] = (_Float16)((u0.w + v0.w) * linv_r);
            h0[4] = (_Float16)((u1.x + v1.x) * linv_r);
            h0[5] = (_Float16)((u1.y + v1.y) * linv_r);
            h0[6] = (_Float16)((u1.z + v1.z) * linv_r);
            h0[7] = (_Float16)((u1.w + v1.w) * linv_r);
            h1[0] = (_Float16)((u2.x + v2.x) * linv_r);
            h1[1] = (_Float16)((u2.y + v2.y) * linv_r);
            h1[2] = (_Float16)((u2.z + v2.z) * linv_r);
            h1[3] = (_Float16)((u2.w + v2.w) * linv_r);
            h1[4] = (_Float16)((u3.x + v3.x) * linv_r);
            h1[5] = (_Float16)((u3.y + v3.y) * linv_r);
            h1[6] = (_Float16)((u3.z + v3.z) * linv_r);
            h1[7] = (_Float16)((u3.w + v3.w) * linv_r);
            *(f16x8*)&As[arow][ak]     = h0;
            *(f16x8*)&As[arow][ak + 8] = h1;
        }
        {
            const float* wq = wp + kk * DIM;
            f16x8 hb;
            hb[0] = (_Float16)wq[0 * DIM]; hb[1] = (_Float16)wq[1 * DIM];
            hb[2] = (_Float16)wq[2 * DIM]; hb[3] = (_Float16)wq[3 * DIM];
            hb[4] = (_Float16)wq[4 * DIM]; hb[5] = (_Float16)wq[5 * DIM];
            hb[6] = (_Float16)wq[6 * DIM]; hb[7] = (_Float16)wq[7 * DIM];
            *(f16x8*)&Bs[bcol][bsg << 3] = hb;
        }
        __syncthreads();
        const f16x8 af0 = *(const f16x8*)&As[wid * 32 + c][g * 8];
        const f16x8 af1 = *(const f16x8*)&As[wid * 32 + 16 + c][g * 8];
        #pragma unroll
        for (int j = 0; j < 4; ++j) {
            const int bc = j * 16 + c;
            const int gg = g ^ ((bc >> 3) & 3);
            const f16x8 bf = *(const f16x8*)&Bs[bc][gg * 8];
            acc[0][j] = __builtin_amdgcn_mfma_f32_16x16x32_f16(af0, bf, acc[0][j], 0, 0, 0);
            acc[1][j] = __builtin_amdgcn_mfma_f32_16x16x32_f16(af1, bf, acc[1][j], 0, 0, 0);
        }
        __syncthreads();
    }

    #pragma unroll
    for (int i = 0; i < 2; ++i) {
        const int gr = r0 + wid * 32 + i * 16 + 4 * g;
        #pragma unroll
        for (int j = 0; j < 4; ++j) {
            const int col  = c0 + j * 16 + c;
            const float bv = bias[col];
            const f32x4 a  = acc[i][j];
            out[(gr + 0) * DIM + col] = a[0] + bv;
            out[(gr + 1) * DIM + col] = a[1] + bv;
            out[(gr + 2) * DIM + col] = a[2] + bv;
            out[(gr + 3) * DIM + col] = a[3] + bv;
        }
    }
}

extern "C" void kernel_launch(void* const* d_in, const int* in_sizes, int n_in,
                              void* d_out, int out_size, void* d_ws, size_t ws_size,
                              hipStream_t stream)
{
    const float* x0    = (const float*)d_in[0];
    const float* x1    = (const float*)d_in[1];
    const float* x2    = (const float*)d_in[2];
    const float* x3    = (const float*)d_in[3];
    const float* Wqkv  = (const float*)d_in[4];
    const float* bqkv  = (const float*)d_in[5];
    const float* Wproj = (const float*)d_in[6];
    const float* bproj = (const float*)d_in[7];
    _Float16* wsh = (_Float16*)d_ws;
    float*    wsf = (float*)d_ws;
    float*    out = (float*)d_out;

    // 1) QKV projection: 12 col-tiles x 24 row-tiles(128) x 4 mods
    qkv_mfma_kernel<<<dim3(12, 24, 4), 256, 0, stream>>>(
        x0, x1, x2, x3, Wqkv, bqkv, wsh);

    // 2) attention: 1152 blocks x 4 waves, 128-key LDS staging tiles
    attn_mfma_kernel<<<dim3(1152), 256, 0, stream>>>(wsh, wsf);

    // 3) output projection (+ partial combine + normalize): 4 x 72 tiles
    proj_mfma_kernel<<<dim3(4, 72), 256, 0, stream>>>(wsf, Wproj, bproj, out);
}